// Round 8
// baseline (298.222 us; speedup 1.0000x reference)
//
#include <hip/hip_runtime.h>
#include <math.h>

#define BB 8
#define SS 4096
#define DD 1024
#define KK 3072
#define NCHUNK 8
#define CHUNK 512          // SS / NCHUNK candidates per rank chunk
#define NELEM (BB * SS)    // 32768

typedef unsigned long long u64;
typedef unsigned int u32;
typedef float f32x4 __attribute__((ext_vector_type(4)));

// ---- ws layout (bytes) ----
#define OFF_KEYS    0            // 32768 * 8  = 262144
#define OFF_SCORES  262144       // 32768 * 4  = 131072
#define OFF_RANK    393216       // 32768 * 4  = 131072
#define OFF_PCNT    524288       // 32768 * 4 * 8 = 1048576
#define OFF_PARTIAL 1572864      // 128 * 4 = 512
#define OFF_FLAGS   1573888      // 144 ints (done[8], rdone[128], pdone[8])

// =======================================================================
// Fused persistent kernel: 1024 blocks x 256 threads, 4 blocks/CU
// co-resident by construction (grid 1024 <= 256 CU * 4 blocks).
// P1 scores -> done[b] -> P2 ballot-rank chunk -> rdone[ob] ->
// P3 finalize (blocks 0..127) -> pdone[b] -> P4 blend.
// All cross-block handoffs via device-scope release/acquire counters.
// FP summation orders identical to the proven 4-kernel version.
// =======================================================================
__global__ __launch_bounds__(256, 4) void mod_fused(
    const float* __restrict__ x, const float* __restrict__ proc,
    const float* __restrict__ w, float* __restrict__ out,
    u64* __restrict__ keys, float* __restrict__ scores,
    int* __restrict__ rank_of, int* __restrict__ pcnt,
    float* __restrict__ partial, int* flags)
{
    __shared__ __align__(16) u64 lk[CHUNK];   // 4 KB
    __shared__ float red[256];                // 1 KB
    int* done  = flags;        // [8]   target 128
    int* rdone = flags + 8;    // [128] target 8
    int* pdone = flags + 136;  // [8]   target 16

    const int bid  = blockIdx.x;     // 0..1023
    const int tid  = threadIdx.x;
    const int lane = tid & 63;
    const int wv   = tid >> 6;       // 0..3
    const int row0  = bid * 32;      // this block's 32 rows (one batch)
    const int batch = row0 >> 12;    // 128 blocks per batch

    // ---------------- P1: scores + sortable keys ----------------
    {
        const float4* wr = (const float4*)w;
        float4 wl[4];
#pragma unroll
        for (int i = 0; i < 4; ++i) wl[i] = wr[lane + 64 * i];
        for (int r = 0; r < 8; ++r) {
            int row = row0 + wv * 8 + r;
            const float4* xr = (const float4*)(x + (size_t)row * DD);
            float acc = 0.f;
#pragma unroll
            for (int i = 0; i < 4; ++i) {
                float4 a = xr[lane + 64 * i];
                float4 b = wl[i];
                acc += a.x * b.x + a.y * b.y + a.z * b.z + a.w * b.w;
            }
#pragma unroll
            for (int off = 32; off > 0; off >>= 1)
                acc += __shfl_down(acc, off, 64);
            if (lane == 0) {
                scores[row] = acc;
                u32 u = __float_as_uint(acc);
                u32 m = (u & 0x80000000u) ? ~u : (u | 0x80000000u);
                keys[row] = ((u64)(~m) << 32) | (u32)(row & (SS - 1));
            }
        }
    }
    __syncthreads();   // all waves' stores complete (vmcnt drained per thread)
    if (tid == 0) {
        __threadfence();
        __hip_atomic_fetch_add(&done[batch], 1, __ATOMIC_RELEASE, __HIP_MEMORY_SCOPE_AGENT);
    }

    // ---------------- P2: ballot-rank chunk (ob, c) ----------------
    const int ob = bid >> 3;          // 0..127
    const int c  = bid & 7;
    const int b2 = ob >> 4;           // == batch, kept explicit
    if (tid == 0) {
        while (__hip_atomic_load(&done[b2], __ATOMIC_ACQUIRE, __HIP_MEMORY_SCOPE_AGENT) < 128)
            __builtin_amdgcn_s_sleep(8);
    }
    __syncthreads();
    {
        const u64* __restrict__ cand = keys + ((size_t)b2 << 12) + c * CHUNK;
        *(ulonglong2*)&lk[tid * 2] = *(const ulonglong2*)&cand[tid * 2];
        const int gid2 = ob * 256 + tid;
        const u64 my = keys[gid2];
        __syncthreads();

        const u32 my_hi = (u32)(my >> 32);
        const u32 my_lo = (u32)my;
        int v_cnt = 0;
#pragma unroll
        for (int g = 0; g < 8; ++g) {
            u64 mj[8];
#pragma unroll
            for (int j = 0; j < 8; ++j) {
                u32 h = (u32)__builtin_amdgcn_readlane((int)my_hi, g * 8 + j);
                u32 l = (u32)__builtin_amdgcn_readlane((int)my_lo, g * 8 + j);
                mj[j] = ((u64)h << 32) | l;
            }
            int cnt[8] = {0, 0, 0, 0, 0, 0, 0, 0};
#pragma unroll
            for (int cg = 0; cg < CHUNK / 64; ++cg) {
                u64 cv = lk[cg * 64 + lane];
#pragma unroll
                for (int j = 0; j < 8; ++j)
                    cnt[j] += (int)__popcll(__ballot(cv < mj[j]));
            }
#pragma unroll
            for (int j = 0; j < 8; ++j)
                v_cnt = (lane == g * 8 + j) ? cnt[j] : v_cnt;
        }
        pcnt[c * NELEM + gid2] = v_cnt;
    }
    __syncthreads();
    if (tid == 0) {
        __threadfence();
        __hip_atomic_fetch_add(&rdone[ob], 1, __ATOMIC_RELEASE, __HIP_MEMORY_SCOPE_AGENT);
    }

    // ---------------- P3: finalize (blocks 0..127 -> ob2 = bid) ----------------
    if (bid < 128) {
        if (tid == 0) {
            while (__hip_atomic_load(&rdone[bid], __ATOMIC_ACQUIRE, __HIP_MEMORY_SCOPE_AGENT) < 8)
                __builtin_amdgcn_s_sleep(8);
        }
        __syncthreads();
        const int gid3 = bid * 256 + tid;
        int rr = 0;
#pragma unroll
        for (int cc = 0; cc < NCHUNK; ++cc) rr += pcnt[cc * NELEM + gid3];
        rank_of[gid3] = rr;

        float e = (rr < KK) ? expf(scores[gid3]) : 0.f;
        red[tid] = e;
        __syncthreads();
        for (int off = 128; off > 0; off >>= 1) {
            if (tid < off) red[tid] += red[tid + off];
            __syncthreads();
        }
        if (tid == 0) {
            partial[bid] = red[0];
            __threadfence();
            __hip_atomic_fetch_add(&pdone[bid >> 4], 1, __ATOMIC_RELEASE, __HIP_MEMORY_SCOPE_AGENT);
        }
    }

    // ---------------- P4: blend this block's 32 rows ----------------
    if (tid == 0) {
        while (__hip_atomic_load(&pdone[batch], __ATOMIC_ACQUIRE, __HIP_MEMORY_SCOPE_AGENT) < 16)
            __builtin_amdgcn_s_sleep(8);
    }
    __syncthreads();
    {
        float denom = 0.f;
#pragma unroll
        for (int i = 0; i < 16; ++i) denom += partial[batch * 16 + i];  // deterministic
        for (int r = 0; r < 32; ++r) {
            int row = row0 + r;
            const f32x4* xr = (const f32x4*)(x + (size_t)row * DD);
            f32x4* orow = (f32x4*)(out + (size_t)row * DD);
            int j = rank_of[row];                 // uniform across block
            f32x4 a = xr[tid];
            if (j < KK) {
                float wgt = expf(scores[row]) / denom;
                const f32x4* pr = (const f32x4*)(proc + ((size_t)batch * KK + j) * DD);
                f32x4 p = __builtin_nontemporal_load(pr + tid);
                f32x4 o = p * wgt + (1.f - wgt) * a;
                __builtin_nontemporal_store(o, orow + tid);
            } else {
                __builtin_nontemporal_store(a, orow + tid);
            }
        }
    }
}

extern "C" void kernel_launch(void* const* d_in, const int* in_sizes, int n_in,
                              void* d_out, int out_size, void* d_ws, size_t ws_size,
                              hipStream_t stream) {
    const float* x    = (const float*)d_in[0];   // (B,S,D)
    const float* proc = (const float*)d_in[1];   // (B,K,D)
    const float* w    = (const float*)d_in[2];   // (D,)
    float* out = (float*)d_out;

    u64*   keys    = (u64*)((char*)d_ws + OFF_KEYS);
    float* scores  = (float*)((char*)d_ws + OFF_SCORES);
    int*   rank_of = (int*)((char*)d_ws + OFF_RANK);
    int*   pcnt    = (int*)((char*)d_ws + OFF_PCNT);
    float* partial = (float*)((char*)d_ws + OFF_PARTIAL);
    int*   flags   = (int*)((char*)d_ws + OFF_FLAGS);

    // flags must be zero at kernel start on EVERY call (ws is poisoned once
    // and never re-poisoned); async memset is graph-capture-safe.
    hipMemsetAsync(flags, 0, 1024, stream);
    mod_fused<<<1024, 256, 0, stream>>>(x, proc, w, out, keys, scores,
                                        rank_of, pcnt, partial, flags);
}

// Round 9
// 258.204 us; speedup vs baseline: 1.1550x; 1.1550x over previous
//
#include <hip/hip_runtime.h>
#include <math.h>

#define BB 8
#define SS 4096
#define DD 1024
#define KK 3072
#define NCHUNK 8
#define CHUNK 512          // SS / NCHUNK candidates per rank chunk
#define NELEM (BB * SS)    // 32768

typedef unsigned long long u64;
typedef unsigned int u32;
typedef float f32x4 __attribute__((ext_vector_type(4)));

// ---- ws layout (bytes) ----
#define OFF_KEYS    0            // 32768 * 8  = 262144
#define OFF_SCORES  262144       // 32768 * 4  = 131072
#define OFF_RANK    393216       // 32768 * 4  = 131072
#define OFF_PCNT    524288       // 32768 * 4 * 8 = 1048576
#define OFF_PARTIAL 1572864      // 128 * 4 = 512
#define OFF_FLAGS   1573888      // f1[1024] f2[1024] f3[128] = 8704 B
#define FLAGS_BYTES (2176 * 4)

// One wave polls n (<=128) flags with acquire loads; NO RMW anywhere, so no
// cross-XCD cache-line ownership ping-pong (round-8 lesson: 1024 atomic adds
// to one line cost ~250 us).
__device__ __forceinline__ void wait_flags(const int* f, int n, int tid) {
    if (tid < 64) {
        const int lane = tid;
        for (;;) {
            int ok = 1;
            for (int i = lane; i < n; i += 64)
                ok &= __hip_atomic_load(&f[i], __ATOMIC_ACQUIRE, __HIP_MEMORY_SCOPE_AGENT);
            if (__all(ok)) break;
            __builtin_amdgcn_s_sleep(2);
        }
    }
    __syncthreads();
}

__device__ __forceinline__ void signal_flag(int* f, int tid) {
    __syncthreads();
    if (tid == 0) {
        __threadfence();   // release all prior global stores to device scope
        __hip_atomic_store(f, 1, __ATOMIC_RELEASE, __HIP_MEMORY_SCOPE_AGENT);
    }
}

// =======================================================================
// Fused persistent kernel: 1024 blocks x 256 threads, 4 blocks/CU -> all
// co-resident (grid == 256 CU x 4). Per-batch flag barriers (store+poll).
// P1 scores -> f1 -> P2 ballot-rank chunk -> f2 -> P3 finalize (bid&7==0)
// -> f3 -> P4 blend. FP orders identical to the proven 4-kernel version.
// =======================================================================
__global__ __launch_bounds__(256, 4) void mod_fused(
    const float* __restrict__ x, const float* __restrict__ proc,
    const float* __restrict__ w, float* __restrict__ out,
    u64* __restrict__ keys, float* __restrict__ scores,
    int* __restrict__ rank_of, int* __restrict__ pcnt,
    float* __restrict__ partial, int* flags)
{
    __shared__ __align__(16) u64 lk[CHUNK];   // 4 KB
    __shared__ float red[256];                // 1 KB
    int* f1 = flags;          // [1024] P1 done per block
    int* f2 = flags + 1024;   // [1024] P2 done per block
    int* f3 = flags + 2048;   // [128]  P3 done per ob

    const int bid  = blockIdx.x;     // 0..1023
    const int tid  = threadIdx.x;
    const int lane = tid & 63;
    const int wv   = tid >> 6;       // 0..3
    const int row0  = bid * 32;      // this block's 32 rows (one batch)
    const int batch = row0 >> 12;    // 128 blocks per batch

    // ---------------- P1: scores + sortable keys ----------------
    {
        const float4* wr = (const float4*)w;
        float4 wl[4];
#pragma unroll
        for (int i = 0; i < 4; ++i) wl[i] = wr[lane + 64 * i];
        for (int r = 0; r < 8; ++r) {
            int row = row0 + wv * 8 + r;
            const float4* xr = (const float4*)(x + (size_t)row * DD);
            float acc = 0.f;
#pragma unroll
            for (int i = 0; i < 4; ++i) {
                float4 a = xr[lane + 64 * i];
                float4 b = wl[i];
                acc += a.x * b.x + a.y * b.y + a.z * b.z + a.w * b.w;
            }
#pragma unroll
            for (int off = 32; off > 0; off >>= 1)
                acc += __shfl_down(acc, off, 64);
            if (lane == 0) {
                scores[row] = acc;
                u32 u = __float_as_uint(acc);
                u32 m = (u & 0x80000000u) ? ~u : (u | 0x80000000u);
                keys[row] = ((u64)(~m) << 32) | (u32)(row & (SS - 1));
            }
        }
    }
    signal_flag(&f1[bid], tid);

    // ---------------- P2: ballot-rank chunk (ob, c) ----------------
    const int ob = bid >> 3;          // 0..127
    const int c  = bid & 7;
    wait_flags(&f1[batch * 128], 128, tid);   // whole batch's keys ready
    {
        const u64* __restrict__ cand = keys + ((size_t)batch << 12) + c * CHUNK;
        *(ulonglong2*)&lk[tid * 2] = *(const ulonglong2*)&cand[tid * 2];
        const int gid2 = ob * 256 + tid;
        const u64 my = keys[gid2];
        __syncthreads();

        const u32 my_hi = (u32)(my >> 32);
        const u32 my_lo = (u32)my;
        int v_cnt = 0;
#pragma unroll
        for (int g = 0; g < 8; ++g) {
            u64 mj[8];
#pragma unroll
            for (int j = 0; j < 8; ++j) {
                u32 h = (u32)__builtin_amdgcn_readlane((int)my_hi, g * 8 + j);
                u32 l = (u32)__builtin_amdgcn_readlane((int)my_lo, g * 8 + j);
                mj[j] = ((u64)h << 32) | l;
            }
            int cnt[8] = {0, 0, 0, 0, 0, 0, 0, 0};
#pragma unroll
            for (int cg = 0; cg < CHUNK / 64; ++cg) {
                u64 cv = lk[cg * 64 + lane];
#pragma unroll
                for (int j = 0; j < 8; ++j)
                    cnt[j] += (int)__popcll(__ballot(cv < mj[j]));
            }
#pragma unroll
            for (int j = 0; j < 8; ++j)
                v_cnt = (lane == g * 8 + j) ? cnt[j] : v_cnt;
        }
        pcnt[c * NELEM + ob * 256 + tid] = v_cnt;
    }
    signal_flag(&f2[bid], tid);

    // ---------------- P3: finalize (chunk-0 block of each ob) ----------------
    if ((bid & 7) == 0) {
        wait_flags(&f2[ob * 8], 8, tid);      // all 8 chunks of this ob done
        const int gid3 = ob * 256 + tid;
        int rr = 0;
#pragma unroll
        for (int cc = 0; cc < NCHUNK; ++cc) rr += pcnt[cc * NELEM + gid3];
        rank_of[gid3] = rr;

        float e = (rr < KK) ? expf(scores[gid3]) : 0.f;
        red[tid] = e;
        __syncthreads();
        for (int off = 128; off > 0; off >>= 1) {
            if (tid < off) red[tid] += red[tid + off];
            __syncthreads();
        }
        if (tid == 0) partial[ob] = red[0];
        signal_flag(&f3[ob], tid);
    }

    // ---------------- P4: blend this block's 32 rows ----------------
    wait_flags(&f3[batch * 16], 16, tid);     // batch's ranks + partials ready
    {
        float denom = 0.f;
#pragma unroll
        for (int i = 0; i < 16; ++i) denom += partial[batch * 16 + i];  // deterministic
        for (int r = 0; r < 32; ++r) {
            int row = row0 + r;
            const f32x4* xr = (const f32x4*)(x + (size_t)row * DD);
            f32x4* orow = (f32x4*)(out + (size_t)row * DD);
            int j = rank_of[row];                 // uniform across block
            f32x4 a = xr[tid];
            if (j < KK) {
                float wgt = expf(scores[row]) / denom;
                const f32x4* pr = (const f32x4*)(proc + ((size_t)batch * KK + j) * DD);
                f32x4 p = __builtin_nontemporal_load(pr + tid);
                f32x4 o = p * wgt + (1.f - wgt) * a;
                __builtin_nontemporal_store(o, orow + tid);
            } else {
                __builtin_nontemporal_store(a, orow + tid);
            }
        }
    }
}

extern "C" void kernel_launch(void* const* d_in, const int* in_sizes, int n_in,
                              void* d_out, int out_size, void* d_ws, size_t ws_size,
                              hipStream_t stream) {
    const float* x    = (const float*)d_in[0];   // (B,S,D)
    const float* proc = (const float*)d_in[1];   // (B,K,D)
    const float* w    = (const float*)d_in[2];   // (D,)
    float* out = (float*)d_out;

    u64*   keys    = (u64*)((char*)d_ws + OFF_KEYS);
    float* scores  = (float*)((char*)d_ws + OFF_SCORES);
    int*   rank_of = (int*)((char*)d_ws + OFF_RANK);
    int*   pcnt    = (int*)((char*)d_ws + OFF_PCNT);
    float* partial = (float*)((char*)d_ws + OFF_PARTIAL);
    int*   flags   = (int*)((char*)d_ws + OFF_FLAGS);

    // flags must be zero at kernel start on EVERY call (ws poisoned once,
    // never re-poisoned); async memset is graph-capture-safe.
    hipMemsetAsync(flags, 0, FLAGS_BYTES, stream);
    mod_fused<<<1024, 256, 0, stream>>>(x, proc, w, out, keys, scores,
                                        rank_of, pcnt, partial, flags);
}

// Round 10
// 227.994 us; speedup vs baseline: 1.3080x; 1.1325x over previous
//
#include <hip/hip_runtime.h>
#include <math.h>

#define BB 8
#define SS 4096
#define DD 1024
#define KK 3072
#define NCHUNK 8
#define CHUNK 512          // SS / NCHUNK candidates per rank chunk
#define NELEM (BB * SS)    // 32768

typedef unsigned long long u64;
typedef unsigned int u32;
typedef float f32x4 __attribute__((ext_vector_type(4)));

// ---- ws layout (bytes) ----
#define OFF_KEYS    0            // 32768 * 8  = 262144
#define OFF_SCORES  262144       // 32768 * 4  = 131072
#define OFF_RANK    393216       // 32768 * 4  = 131072
#define OFF_PCNT    524288       // 32768 * 4 * 8 = 1048576
#define OFF_PARTIAL 1572864      // 128 * 4 = 512
#define OFF_FLAGS   1573888      // f1[1024] f2[1024] f3[128]
#define FLAGS_BYTES (2176 * 4)

// Round-8/9 lesson: agent-scope ACQUIRE loads in a poll loop invalidate the
// XCD L2 (buffer_inv sc1) EVERY iteration -> chip-wide cache-invalidate storm
// (300 us). Poll with RELAXED atomic loads (coherence-point access, visible
// updates, NO invalidate), then ONE acquire fence after the predicate passes.
__device__ __forceinline__ void wait_flags(const int* f, int n, int tid) {
    if (tid < 64) {
        for (;;) {
            int ok = 1;
            for (int i = tid; i < n; i += 64)
                ok &= __hip_atomic_load(&f[i], __ATOMIC_RELAXED, __HIP_MEMORY_SCOPE_AGENT);
            if (__all(ok)) break;
            __builtin_amdgcn_s_sleep(2);
        }
    }
    __syncthreads();
    __builtin_amdgcn_fence(__ATOMIC_ACQUIRE, "agent");   // one L1/L2 inv total
}

__device__ __forceinline__ void signal_flag(int* f, int tid) {
    __syncthreads();   // each wave drains its own stores (vmcnt) before barrier
    if (tid == 0) {
        __builtin_amdgcn_fence(__ATOMIC_RELEASE, "agent");  // one L2 writeback
        __hip_atomic_store(f, 1, __ATOMIC_RELAXED, __HIP_MEMORY_SCOPE_AGENT);
    }
}

// =======================================================================
// Fused persistent kernel: 1024 blocks x 256 threads, 4 blocks/CU -> all
// co-resident (grid == 256 CU x 4). Per-batch flag barriers (store+poll).
// P1 scores -> f1 -> P2 ballot-rank chunk -> f2 -> P3 finalize (bid&7==0)
// -> f3 -> P4 blend. FP orders identical to the proven 4-kernel version.
// =======================================================================
__global__ __launch_bounds__(256, 4) void mod_fused(
    const float* __restrict__ x, const float* __restrict__ proc,
    const float* __restrict__ w, float* __restrict__ out,
    u64* __restrict__ keys, float* __restrict__ scores,
    int* __restrict__ rank_of, int* __restrict__ pcnt,
    float* __restrict__ partial, int* flags)
{
    __shared__ __align__(16) u64 lk[CHUNK];   // 4 KB
    __shared__ float red[256];                // 1 KB
    int* f1 = flags;          // [1024] P1 done per block
    int* f2 = flags + 1024;   // [1024] P2 done per block
    int* f3 = flags + 2048;   // [128]  P3 done per ob

    const int bid  = blockIdx.x;     // 0..1023
    const int tid  = threadIdx.x;
    const int lane = tid & 63;
    const int wv   = tid >> 6;       // 0..3
    const int row0  = bid * 32;      // this block's 32 rows (one batch)
    const int batch = row0 >> 12;    // 128 blocks per batch

    // ---------------- P1: scores + sortable keys ----------------
    {
        const float4* wr = (const float4*)w;
        float4 wl[4];
#pragma unroll
        for (int i = 0; i < 4; ++i) wl[i] = wr[lane + 64 * i];
        for (int r = 0; r < 8; ++r) {
            int row = row0 + wv * 8 + r;
            const float4* xr = (const float4*)(x + (size_t)row * DD);
            float acc = 0.f;
#pragma unroll
            for (int i = 0; i < 4; ++i) {
                float4 a = xr[lane + 64 * i];
                float4 b = wl[i];
                acc += a.x * b.x + a.y * b.y + a.z * b.z + a.w * b.w;
            }
#pragma unroll
            for (int off = 32; off > 0; off >>= 1)
                acc += __shfl_down(acc, off, 64);
            if (lane == 0) {
                scores[row] = acc;
                u32 u = __float_as_uint(acc);
                u32 m = (u & 0x80000000u) ? ~u : (u | 0x80000000u);
                keys[row] = ((u64)(~m) << 32) | (u32)(row & (SS - 1));
            }
        }
    }
    signal_flag(&f1[bid], tid);

    // ---------------- P2: ballot-rank chunk (ob, c) ----------------
    const int ob = bid >> 3;          // 0..127
    const int c  = bid & 7;
    wait_flags(&f1[batch * 128], 128, tid);   // whole batch's keys ready
    {
        const u64* __restrict__ cand = keys + ((size_t)batch << 12) + c * CHUNK;
        *(ulonglong2*)&lk[tid * 2] = *(const ulonglong2*)&cand[tid * 2];
        const int gid2 = ob * 256 + tid;
        const u64 my = keys[gid2];
        __syncthreads();

        const u32 my_hi = (u32)(my >> 32);
        const u32 my_lo = (u32)my;
        int v_cnt = 0;
#pragma unroll
        for (int g = 0; g < 8; ++g) {
            u64 mj[8];
#pragma unroll
            for (int j = 0; j < 8; ++j) {
                u32 h = (u32)__builtin_amdgcn_readlane((int)my_hi, g * 8 + j);
                u32 l = (u32)__builtin_amdgcn_readlane((int)my_lo, g * 8 + j);
                mj[j] = ((u64)h << 32) | l;
            }
            int cnt[8] = {0, 0, 0, 0, 0, 0, 0, 0};
#pragma unroll
            for (int cg = 0; cg < CHUNK / 64; ++cg) {
                u64 cv = lk[cg * 64 + lane];
#pragma unroll
                for (int j = 0; j < 8; ++j)
                    cnt[j] += (int)__popcll(__ballot(cv < mj[j]));
            }
#pragma unroll
            for (int j = 0; j < 8; ++j)
                v_cnt = (lane == g * 8 + j) ? cnt[j] : v_cnt;
        }
        pcnt[c * NELEM + ob * 256 + tid] = v_cnt;
    }
    signal_flag(&f2[bid], tid);

    // ---------------- P3: finalize (chunk-0 block of each ob) ----------------
    if ((bid & 7) == 0) {
        wait_flags(&f2[ob * 8], 8, tid);      // all 8 chunks of this ob done
        const int gid3 = ob * 256 + tid;
        int rr = 0;
#pragma unroll
        for (int cc = 0; cc < NCHUNK; ++cc) rr += pcnt[cc * NELEM + gid3];
        rank_of[gid3] = rr;

        float e = (rr < KK) ? expf(scores[gid3]) : 0.f;
        red[tid] = e;
        __syncthreads();
        for (int off = 128; off > 0; off >>= 1) {
            if (tid < off) red[tid] += red[tid + off];
            __syncthreads();
        }
        if (tid == 0) partial[ob] = red[0];
        signal_flag(&f3[ob], tid);
    }

    // ---------------- P4: blend this block's 32 rows ----------------
    wait_flags(&f3[batch * 16], 16, tid);     // batch's ranks + partials ready
    {
        float denom = 0.f;
#pragma unroll
        for (int i = 0; i < 16; ++i) denom += partial[batch * 16 + i];  // deterministic
        for (int r = 0; r < 32; ++r) {
            int row = row0 + r;
            const f32x4* xr = (const f32x4*)(x + (size_t)row * DD);
            f32x4* orow = (f32x4*)(out + (size_t)row * DD);
            int j = rank_of[row];                 // uniform across block
            f32x4 a = xr[tid];
            if (j < KK) {
                float wgt = expf(scores[row]) / denom;
                const f32x4* pr = (const f32x4*)(proc + ((size_t)batch * KK + j) * DD);
                f32x4 p = __builtin_nontemporal_load(pr + tid);
                f32x4 o = p * wgt + (1.f - wgt) * a;
                __builtin_nontemporal_store(o, orow + tid);
            } else {
                __builtin_nontemporal_store(a, orow + tid);
            }
        }
    }
}

extern "C" void kernel_launch(void* const* d_in, const int* in_sizes, int n_in,
                              void* d_out, int out_size, void* d_ws, size_t ws_size,
                              hipStream_t stream) {
    const float* x    = (const float*)d_in[0];   // (B,S,D)
    const float* proc = (const float*)d_in[1];   // (B,K,D)
    const float* w    = (const float*)d_in[2];   // (D,)
    float* out = (float*)d_out;

    u64*   keys    = (u64*)((char*)d_ws + OFF_KEYS);
    float* scores  = (float*)((char*)d_ws + OFF_SCORES);
    int*   rank_of = (int*)((char*)d_ws + OFF_RANK);
    int*   pcnt    = (int*)((char*)d_ws + OFF_PCNT);
    float* partial = (float*)((char*)d_ws + OFF_PARTIAL);
    int*   flags   = (int*)((char*)d_ws + OFF_FLAGS);

    // flags must be zero at kernel start on EVERY call (ws poisoned once,
    // never re-poisoned); async memset is graph-capture-safe.
    hipMemsetAsync(flags, 0, FLAGS_BYTES, stream);
    mod_fused<<<1024, 256, 0, stream>>>(x, proc, w, out, keys, scores,
                                        rank_of, pcnt, partial, flags);
}

// Round 11
// 95.234 us; speedup vs baseline: 3.1315x; 2.3940x over previous
//
#include <hip/hip_runtime.h>
#include <math.h>

#define BB 8
#define SS 4096
#define DD 1024
#define KK 3072
#define NELEM (BB * SS)    // 32768

typedef unsigned long long u64;
typedef unsigned int u32;
typedef float f32x4 __attribute__((ext_vector_type(4)));

// ---------------- Kernel 1: scores + sortable keys --------------------------------
// One wave (64 lanes) per token row. key = (~mono(score) << 32) | index :
// ascending key == descending score, ties by lower index (lax.top_k stable order).
__global__ __launch_bounds__(256) void mod_scores(const float* __restrict__ x,
                                                  const float* __restrict__ w,
                                                  float* __restrict__ scores,
                                                  u64* __restrict__ keys) {
    int wave = (int)((blockIdx.x * blockDim.x + threadIdx.x) >> 6);
    int lane = threadIdx.x & 63;
    if (wave >= NELEM) return;
    const float4* xr = (const float4*)(x + (size_t)wave * DD);
    const float4* wr = (const float4*)w;
    float acc = 0.f;
#pragma unroll
    for (int i = 0; i < 4; ++i) {
        float4 a = xr[lane + 64 * i];
        float4 b = wr[lane + 64 * i];
        acc += a.x * b.x + a.y * b.y + a.z * b.z + a.w * b.w;
    }
#pragma unroll
    for (int off = 32; off > 0; off >>= 1)
        acc += __shfl_down(acc, off, 64);
    if (lane == 0) {
        scores[wave] = acc;
        u32 u = __float_as_uint(acc);
        u32 m = (u & 0x80000000u) ? ~u : (u | 0x80000000u);  // monotonic ascending
        keys[wave] = ((u64)(~m) << 32) | (u32)(wave & (SS - 1));
    }
}

// ---------------- Kernel 2: single-launch full rank + softmax partials ------------
// 512 blocks x 256 threads; block bid owns 64 rows (gid0 = bid*64, one batch).
// Stage the batch's full 4096 keys in LDS (32 KB). Wave wv ranks all 64 owners
// against its candidate quarter [wv*1024, +1024) via the proven ballot pattern:
// owner keys broadcast via readlane (groups of 8), lane-strided LDS candidate
// reads (unrolled: 16 ds_reads in flight -- round-6 lesson), v_cmp_lt_u64 +
// ballot + popc = 64 pairs/instr. Cross-wave count sum via LDS (intra-block).
// No cross-block deps, no pcnt round-trip, one launch for the whole rank path.
__global__ __launch_bounds__(256) void mod_rank_full(const u64* __restrict__ keys,
                                                     const float* __restrict__ scores,
                                                     int* __restrict__ rank_of,
                                                     float* __restrict__ partial) {
    __shared__ __align__(16) u64 lk[SS];     // 32 KB
    __shared__ int redi[256];
    const int bid  = blockIdx.x;             // 0..511
    const int tid  = threadIdx.x;
    const int lane = tid & 63;
    const int wv   = tid >> 6;               // 0..3
    const int batch = bid >> 6;              // 64 blocks per batch
    const int gid0  = bid * 64;              // owners gid0..gid0+63

    const u64* __restrict__ kb = keys + ((size_t)batch << 12);
#pragma unroll
    for (int i = 0; i < 8; ++i) {            // 2048 ulonglong2 / 256 threads
        int idx = tid + 256 * i;
        *(ulonglong2*)&lk[2 * idx] = *(const ulonglong2*)&kb[2 * idx];
    }
    __syncthreads();

    const u64 my = lk[(bid & 63) * 64 + lane];   // owner keys are in the stage
    const u32 my_hi = (u32)(my >> 32);
    const u32 my_lo = (u32)my;

    int v_cnt = 0;   // lane i accumulates owner-i's count over this wave's quarter
#pragma unroll
    for (int g = 0; g < 8; ++g) {
        u64 mj[8];
#pragma unroll
        for (int j = 0; j < 8; ++j) {
            u32 h = (u32)__builtin_amdgcn_readlane((int)my_hi, g * 8 + j);
            u32 l = (u32)__builtin_amdgcn_readlane((int)my_lo, g * 8 + j);
            mj[j] = ((u64)h << 32) | l;
        }
        int cnt[8] = {0, 0, 0, 0, 0, 0, 0, 0};
#pragma unroll
        for (int cg = 0; cg < 16; ++cg) {            // unrolled: reads stay in flight
            u64 cv = lk[wv * 1024 + cg * 64 + lane]; // 64 candidates per read
#pragma unroll
            for (int j = 0; j < 8; ++j)
                cnt[j] += (int)__popcll(__ballot(cv < mj[j]));  // 64 pairs / v_cmp
        }
#pragma unroll
        for (int j = 0; j < 8; ++j)                   // cnt[j] is wave-uniform
            v_cnt = (lane == g * 8 + j) ? cnt[j] : v_cnt;
    }
    redi[tid] = v_cnt;                                // redi[wv*64 + lane]
    __syncthreads();

    if (wv == 0) {
        int r = redi[lane] + redi[64 + lane] + redi[128 + lane] + redi[192 + lane];
        rank_of[gid0 + lane] = r;
        float e = (r < KK) ? expf(scores[gid0 + lane]) : 0.f;
#pragma unroll
        for (int off = 32; off > 0; off >>= 1)
            e += __shfl_down(e, off, 64);
        if (lane == 0) partial[bid] = e;              // 64 partials per batch
    }
}

// ---------------- Kernel 3: blend/copy per token row ------------------------------
// x loads regular (L3-resident from kernel 1); proc loads / out stores are
// non-temporal (neutral but harmless; keeps x from being evicted).
__global__ __launch_bounds__(256) void mod_blend(const float* __restrict__ x,
                                                 const float* __restrict__ proc,
                                                 const int* __restrict__ rank_of,
                                                 const float* __restrict__ scores,
                                                 const float* __restrict__ partial,
                                                 float* __restrict__ out) {
    const int row = blockIdx.x;           // b*S + s
    const int b = row >> 12;
    const int t = threadIdx.x;
    const f32x4* xr = (const f32x4*)(x + (size_t)row * DD);
    f32x4* orow = (f32x4*)(out + (size_t)row * DD);
    const int j = rank_of[row];           // uniform per block -> scalar load
    f32x4 a = xr[t];
    if (j < KK) {
        float denom = 0.f;
#pragma unroll
        for (int i = 0; i < 64; ++i) denom += partial[b * 64 + i];  // deterministic
        float w = expf(scores[row]) / denom;
        const f32x4* pr = (const f32x4*)(proc + ((size_t)b * KK + j) * DD);
        f32x4 p = __builtin_nontemporal_load(pr + t);
        f32x4 o = p * w + (1.f - w) * a;
        __builtin_nontemporal_store(o, orow + t);
    } else {
        __builtin_nontemporal_store(a, orow + t);
    }
}

extern "C" void kernel_launch(void* const* d_in, const int* in_sizes, int n_in,
                              void* d_out, int out_size, void* d_ws, size_t ws_size,
                              hipStream_t stream) {
    const float* x    = (const float*)d_in[0];   // (B,S,D)
    const float* proc = (const float*)d_in[1];   // (B,K,D)
    const float* w    = (const float*)d_in[2];   // (D,)
    float* out = (float*)d_out;

    // workspace layout
    u64*   keys    = (u64*)d_ws;                                   // 256 KB
    float* scores  = (float*)((char*)d_ws + NELEM * 8);            // 128 KB
    int*   rank_of = (int*)((char*)d_ws + NELEM * 12);             // 128 KB
    float* partial = (float*)((char*)d_ws + NELEM * 16);           // 2 KB

    mod_scores   <<<NELEM / 4, 256, 0, stream>>>(x, w, scores, keys);
    mod_rank_full<<<NELEM / 64, 256, 0, stream>>>(keys, scores, rank_of, partial);
    mod_blend    <<<NELEM, 256, 0, stream>>>(x, proc, rank_of, scores, partial, out);
}

// Round 12
// 91.523 us; speedup vs baseline: 3.2584x; 1.0405x over previous
//
#include <hip/hip_runtime.h>
#include <math.h>

#define BB 8
#define SS 4096
#define DD 1024
#define KK 3072
#define NCHUNK 8
#define CHUNK 512          // SS / NCHUNK candidates per block
#define NELEM (BB * SS)    // 32768

typedef unsigned long long u64;
typedef unsigned int u32;
typedef float f32x4 __attribute__((ext_vector_type(4)));

// ---------------- Kernel 1: scores + sortable keys --------------------------------
// One wave (64 lanes) per token row. key = (~mono(score) << 32) | index :
// ascending key == descending score, ties by lower index (lax.top_k stable order).
__global__ __launch_bounds__(256) void mod_scores(const float* __restrict__ x,
                                                  const float* __restrict__ w,
                                                  float* __restrict__ scores,
                                                  u64* __restrict__ keys) {
    int wave = (int)((blockIdx.x * blockDim.x + threadIdx.x) >> 6);
    int lane = threadIdx.x & 63;
    if (wave >= NELEM) return;
    const float4* xr = (const float4*)(x + (size_t)wave * DD);
    const float4* wr = (const float4*)w;
    float acc = 0.f;
#pragma unroll
    for (int i = 0; i < 4; ++i) {
        float4 a = xr[lane + 64 * i];
        float4 b = wr[lane + 64 * i];
        acc += a.x * b.x + a.y * b.y + a.z * b.z + a.w * b.w;
    }
#pragma unroll
    for (int off = 32; off > 0; off >>= 1)
        acc += __shfl_down(acc, off, 64);
    if (lane == 0) {
        scores[wave] = acc;
        u32 u = __float_as_uint(acc);
        u32 m = (u & 0x80000000u) ? ~u : (u | 0x80000000u);  // monotonic ascending
        keys[wave] = ((u64)(~m) << 32) | (u32)(wave & (SS - 1));
    }
}

// ---------------- Kernel 2: tiled partial rank (ballot-vectorized, round-5 proven) -
__global__ __launch_bounds__(256) void mod_rank_partial(const u64* __restrict__ keys,
                                                        int* __restrict__ pcnt) {
    __shared__ __align__(16) u64 lk[CHUNK];
    const int ob = blockIdx.x / NCHUNK;
    const int c  = blockIdx.x - ob * NCHUNK;
    const int tid = threadIdx.x;
    const int gid = ob * 256 + tid;
    const int b = gid >> 12;
    const int lane = tid & 63;

    const u64* __restrict__ cand = keys + ((size_t)b << 12) + c * CHUNK;
    *(ulonglong2*)&lk[tid * 2] = *(const ulonglong2*)&cand[tid * 2];
    __syncthreads();

    const u64 my = keys[gid];
    const u32 my_hi = (u32)(my >> 32);
    const u32 my_lo = (u32)my;

    int v_cnt = 0;   // lane i ends up holding owner-i's count
#pragma unroll
    for (int g = 0; g < 8; ++g) {
        u64 mj[8];
#pragma unroll
        for (int j = 0; j < 8; ++j) {
            u32 h = (u32)__builtin_amdgcn_readlane((int)my_hi, g * 8 + j);
            u32 l = (u32)__builtin_amdgcn_readlane((int)my_lo, g * 8 + j);
            mj[j] = ((u64)h << 32) | l;
        }
        int cnt[8] = {0, 0, 0, 0, 0, 0, 0, 0};
#pragma unroll
        for (int cg = 0; cg < CHUNK / 64; ++cg) {   // 8 iterations, unrolled
            u64 cv = lk[cg * 64 + lane];            // lane-strided: 64 cands / read
#pragma unroll
            for (int j = 0; j < 8; ++j)
                cnt[j] += (int)__popcll(__ballot(cv < mj[j]));  // 64 pairs / v_cmp
        }
#pragma unroll
        for (int j = 0; j < 8; ++j)                  // cnt[j] is wave-uniform
            v_cnt = (lane == g * 8 + j) ? cnt[j] : v_cnt;
    }
    pcnt[c * NELEM + gid] = v_cnt;
}

// ---------------- Kernel 3: finalize rank + partial softmax denominator -----------
__global__ __launch_bounds__(256) void mod_finalize(const int* __restrict__ pcnt,
                                                    const float* __restrict__ scores,
                                                    int* __restrict__ rank_of,
                                                    float* __restrict__ partial) {
    const int gid = blockIdx.x * 256 + threadIdx.x;
    int r = 0;
#pragma unroll
    for (int c = 0; c < NCHUNK; ++c) r += pcnt[c * NELEM + gid];
    rank_of[gid] = r;

    float e = (r < KK) ? expf(scores[gid]) : 0.f;
    __shared__ float red[256];
    red[threadIdx.x] = e;
    __syncthreads();
    for (int off = 128; off > 0; off >>= 1) {
        if (threadIdx.x < off) red[threadIdx.x] += red[threadIdx.x + off];
        __syncthreads();
    }
    if (threadIdx.x == 0) partial[blockIdx.x] = red[0];
}

// ---------------- Kernel 4: blend/copy per token row, DESCENDING row order --------
// Scores streamed x ascending -> at blend start, high rows are MRU in the
// Infinity Cache. Reading MRU-first (descending) maximizes hits before the
// proc/out streaming pollution evicts the older (low-row) lines.
__global__ __launch_bounds__(256) void mod_blend(const float* __restrict__ x,
                                                 const float* __restrict__ proc,
                                                 const int* __restrict__ rank_of,
                                                 const float* __restrict__ scores,
                                                 const float* __restrict__ partial,
                                                 float* __restrict__ out) {
    const int row = (NELEM - 1) - blockIdx.x;   // descending: MRU x rows first
    const int b = row >> 12;
    const int t = threadIdx.x;
    const f32x4* xr = (const f32x4*)(x + (size_t)row * DD);
    f32x4* orow = (f32x4*)(out + (size_t)row * DD);
    const int j = rank_of[row];           // uniform per block -> scalar load
    f32x4 a = xr[t];
    if (j < KK) {
        float denom = 0.f;
#pragma unroll
        for (int i = 0; i < 16; ++i) denom += partial[b * 16 + i];  // deterministic
        float w = expf(scores[row]) / denom;
        const f32x4* pr = (const f32x4*)(proc + ((size_t)b * KK + j) * DD);
        f32x4 p = __builtin_nontemporal_load(pr + t);
        f32x4 o = p * w + (1.f - w) * a;
        __builtin_nontemporal_store(o, orow + t);
    } else {
        __builtin_nontemporal_store(a, orow + t);
    }
}

extern "C" void kernel_launch(void* const* d_in, const int* in_sizes, int n_in,
                              void* d_out, int out_size, void* d_ws, size_t ws_size,
                              hipStream_t stream) {
    const float* x    = (const float*)d_in[0];   // (B,S,D)
    const float* proc = (const float*)d_in[1];   // (B,K,D)
    const float* w    = (const float*)d_in[2];   // (D,)
    float* out = (float*)d_out;

    // workspace layout
    u64*   keys    = (u64*)d_ws;                                   // 256 KB
    float* scores  = (float*)((char*)d_ws + NELEM * 8);            // 128 KB
    int*   rank_of = (int*)((char*)d_ws + NELEM * 12);             // 128 KB
    int*   pcnt    = (int*)((char*)d_ws + NELEM * 16);             // 1 MB
    float* partial = (float*)((char*)d_ws + NELEM * 16 + NELEM * 4 * NCHUNK); // 512 B

    mod_scores      <<<NELEM / 4, 256, 0, stream>>>(x, w, scores, keys);
    mod_rank_partial<<<(NELEM / 256) * NCHUNK, 256, 0, stream>>>(keys, pcnt);
    mod_finalize    <<<NELEM / 256, 256, 0, stream>>>(pcnt, scores, rank_of, partial);
    mod_blend       <<<NELEM, 256, 0, stream>>>(x, proc, rank_of, scores, partial, out);
}